// Round 7
// baseline (1212.602 us; speedup 1.0000x reference)
//
#include <hip/hip_runtime.h>
#include <hip/hip_bf16.h>
#include <math.h>

// DualMAR: 2-layer weighted GCN over 100K nodes / 3.2M edges + code/visit
// attention + MLP decoder.
// R6: hist+fill (3.2M device atomics + random 8B scatter wall, ~305us) replaced
// by 32-dst binned partition (LDS-ranked, 32B runs, 800K reserve atomics) +
// bin-local agg (4-wave block per bin, 8 VGPR-resident rows per wave,
// shfl-broadcast edge scan). GEMM/attention/decoder unchanged from R4/R5.

#define D 256
#define BPAT 64
#define VIS 50
#define CODES 64
#define NEG_INF -1e9f
#define MPAD 100096   // 782 * 128 (NN=100000 padded to BM=128)
#define BINB 32       // dsts per bin
#define NBIN 3125     // 3125 * 32 = 100000 exactly

typedef unsigned short ushort_t;
typedef short short8 __attribute__((ext_vector_type(8)));
typedef float f32x4 __attribute__((ext_vector_type(4)));

__device__ __forceinline__ float blo(unsigned u) { return __uint_as_float(u << 16); }
__device__ __forceinline__ float bhi(unsigned u) { return __uint_as_float(u & 0xffff0000u); }
__device__ __forceinline__ float bf2f(ushort_t u) { return __uint_as_float((unsigned)u << 16); }
__device__ __forceinline__ ushort_t f2bfu(float f) {
    __hip_bfloat16 h = __float2bfloat16(f);
    return *reinterpret_cast<ushort_t*>(&h);
}
__device__ __forceinline__ unsigned pack2(float a, float b) {
    return (unsigned)f2bfu(a) | ((unsigned)f2bfu(b) << 16);
}

// ---------------- binned edge partition ----------------

// P1: per-bin edge counts (LDS-aggregated histogram)
__global__ __launch_bounds__(512) void bin_count_kernel(
    const int* __restrict__ ei, int* __restrict__ bincount, int ne) {
    __shared__ int h[NBIN];
    for (int i = threadIdx.x; i < NBIN; i += 512) h[i] = 0;
    __syncthreads();
    int stride = gridDim.x * 512;
    for (int e = blockIdx.x * 512 + threadIdx.x; e < ne; e += stride)
        atomicAdd(&h[ei[(size_t)ne + e] >> 5], 1);
    __syncthreads();
    for (int i = threadIdx.x; i < NBIN; i += 512) {
        int c = h[i];
        if (c) atomicAdd(&bincount[i], c);
    }
}

// P2: exclusive scan of bincount -> binstart, bincursor (single wave)
__global__ __launch_bounds__(64) void bin_scan_kernel(
    const int* __restrict__ bincount, int* __restrict__ binstart,
    int* __restrict__ bincursor) {
    __shared__ int carry;
    int lane = threadIdx.x;
    if (lane == 0) carry = 0;
    __syncthreads();
    for (int base = 0; base < NBIN; base += 64) {
        int i = base + lane;
        int v = (i < NBIN) ? bincount[i] : 0;
        int x = v;
        #pragma unroll
        for (int d = 1; d < 64; d <<= 1) {
            int y = __shfl_up(x, (unsigned)d, 64);
            if (lane >= d) x += y;
        }
        int c = carry;
        if (i < NBIN) { int ex = c + x - v; binstart[i] = ex; bincursor[i] = ex; }
        __syncthreads();
        if (lane == 63) carry = c + x;
        __syncthreads();
    }
}

// P3: partition edges into bin-contiguous pairs array.
// key = src (17b) | (dst&31)<<17; one reserve atomic per (block,bin).
__global__ __launch_bounds__(512) void partition_kernel(
    const int* __restrict__ ei, const float* __restrict__ ew,
    int* __restrict__ bincursor, uint2* __restrict__ pairs, int ne) {
    __shared__ int h[NBIN];
    __shared__ int base_[NBIN];
    for (int i = threadIdx.x; i < NBIN; i += 512) h[i] = 0;
    __syncthreads();
    int stride = gridDim.x * 512;
    for (int e = blockIdx.x * 512 + threadIdx.x; e < ne; e += stride)
        atomicAdd(&h[ei[(size_t)ne + e] >> 5], 1);
    __syncthreads();
    for (int i = threadIdx.x; i < NBIN; i += 512) {
        int c = h[i];
        base_[i] = c ? atomicAdd(&bincursor[i], c) : 0;
        h[i] = 0;
    }
    __syncthreads();
    for (int e = blockIdx.x * 512 + threadIdx.x; e < ne; e += stride) {
        int dd = ei[(size_t)ne + e];
        int ss = ei[e];
        float w = ew[e];
        int bin = dd >> 5;
        int r = atomicAdd(&h[bin], 1);
        pairs[base_[bin] + r] =
            make_uint2((unsigned)ss | ((unsigned)(dd & 31) << 17),
                       __float_as_uint(w));
    }
}

// ---------------- bin-local weighted aggregation ----------------
// One block (4 waves) per 32-dst bin. Wave wid owns rows wid*8..wid*8+7 in
// VGPRs. Edges loaded in 64-wide coalesced chunks, shfl-broadcast per slot;
// ownership branch is wave-uniform. Gather: 8B/lane uint2 (512B row).
__global__ __launch_bounds__(256) void agg_bin_kernel(
    const ushort_t* __restrict__ x,
    const int* __restrict__ binstart, const int* __restrict__ bincount,
    const uint2* __restrict__ pairs, ushort_t* __restrict__ out, int n) {
    int b = blockIdx.x;
    int lane = threadIdx.x & 63, wid = threadIdx.x >> 6;  // 0..3
    int beg = binstart[b], end = beg + bincount[b];
    float4 a0 = {0,0,0,0}, a1 = {0,0,0,0}, a2 = {0,0,0,0}, a3 = {0,0,0,0};
    float4 a4 = {0,0,0,0}, a5 = {0,0,0,0}, a6 = {0,0,0,0}, a7 = {0,0,0,0};

    for (int cb = beg; cb < end; cb += 64) {
        int rem = end - cb;
        uint2 myp = make_uint2(0u, 0u);
        if (lane < rem) myp = pairs[cb + lane];
        int cnt = rem < 64 ? rem : 64;
        for (int s = 0; s < cnt; ++s) {
            unsigned key = __shfl(myp.x, s, 64);
            if ((int)((key >> 20) & 3u) != wid) continue;   // wave-uniform
            float w = __uint_as_float(__shfl(myp.y, s, 64));
            int src = key & 0x1FFFF;
            uint2 v = ((const uint2*)(x + (size_t)src * D))[lane];
            float i0 = w * blo(v.x), i1 = w * bhi(v.x);
            float i2 = w * blo(v.y), i3 = w * bhi(v.y);
            switch ((key >> 17) & 7u) {
                case 0: a0.x+=i0; a0.y+=i1; a0.z+=i2; a0.w+=i3; break;
                case 1: a1.x+=i0; a1.y+=i1; a1.z+=i2; a1.w+=i3; break;
                case 2: a2.x+=i0; a2.y+=i1; a2.z+=i2; a2.w+=i3; break;
                case 3: a3.x+=i0; a3.y+=i1; a3.z+=i2; a3.w+=i3; break;
                case 4: a4.x+=i0; a4.y+=i1; a4.z+=i2; a4.w+=i3; break;
                case 5: a5.x+=i0; a5.y+=i1; a5.z+=i2; a5.w+=i3; break;
                case 6: a6.x+=i0; a6.y+=i1; a6.z+=i2; a6.w+=i3; break;
                case 7: a7.x+=i0; a7.y+=i1; a7.z+=i2; a7.w+=i3; break;
            }
        }
    }

    int dstbase = b * BINB + wid * 8;
#define STORE_ROW(K, A)                                                     \
    {                                                                       \
        int dst = dstbase + (K);                                            \
        if (dst < n) {                                                      \
            uint2 o;                                                        \
            o.x = pack2((A).x, (A).y);                                      \
            o.y = pack2((A).z, (A).w);                                      \
            ((uint2*)(out + (size_t)dst * D))[lane] = o;                    \
        }                                                                   \
    }
    STORE_ROW(0, a0) STORE_ROW(1, a1) STORE_ROW(2, a2) STORE_ROW(3, a3)
    STORE_ROW(4, a4) STORE_ROW(5, a5) STORE_ROW(6, a6) STORE_ROW(7, a7)
#undef STORE_ROW
}

// ---------------- fp32 -> bf16 node table (pad rows zeroed) ----------------
__global__ void cvt_node_kernel(const float* __restrict__ in, ushort_t* __restrict__ out,
                                long n_valid, long n_total) {
    long g = (long)blockIdx.x * blockDim.x + threadIdx.x;
    long ng = n_total >> 2;
    for (long i = g; i < ng; i += (long)gridDim.x * blockDim.x) {
        long e = i << 2;
        uint2 o;
        if (e < n_valid) {
            float4 v = ((const float4*)in)[i];
            o.x = pack2(v.x, v.y);
            o.y = pack2(v.z, v.w);
        } else {
            o.x = 0u; o.y = 0u;
        }
        ((uint2*)out)[i] = o;
    }
}

// ---------------- weight transpose: W[k][n] fp32 -> Wt[n][k] bf16 (256x256) --
__global__ __launch_bounds__(256) void transpose_w_kernel(
    const float* __restrict__ W, ushort_t* __restrict__ Wt) {
    __shared__ float t[32][33];
    int bx = blockIdx.x * 32;   // n base
    int by = blockIdx.y * 32;   // k base
    int lx = threadIdx.x & 31, ly = threadIdx.x >> 5;   // 32 x 8
    #pragma unroll
    for (int i = 0; i < 32; i += 8)
        t[ly + i][lx] = W[(size_t)(by + ly + i) * 256 + bx + lx];
    __syncthreads();
    #pragma unroll
    for (int i = 0; i < 32; i += 8)
        Wt[(size_t)(bx + ly + i) * 256 + by + lx] = f2bfu(t[lx][ly + i]);
}

// ---------------- bf16 MFMA GEMM: 128x256 tile, BK=32, 8 waves (512 thr) ----
// A bf16 row-major [*,256]; Wt = W^T bf16. LDS XOR-swizzle c^=((row>>1)&3).
// MODE 0: relu(A@W+bias) -> bf16 out
// MODE 1: A@W+bias       -> bf16 out
// MODE 2: tout[row] = sum_col tanh((A@W)[row,col]) * u[col]  (no out store)
template<int MODE>
__global__ __launch_bounds__(512) void mfma_gemm_kernel(
    const ushort_t* __restrict__ A, const ushort_t* __restrict__ Wt,
    const float* __restrict__ bias, ushort_t* __restrict__ out,
    const float* __restrict__ u, float* __restrict__ tout, int mvalid) {
    __shared__ __align__(16) ushort_t As[128 * 32];
    __shared__ __align__(16) ushort_t Bs[256 * 32];
    __shared__ float s_t[128];
    const int tid = threadIdx.x;
    const int lane = tid & 63;
    const int wv = tid >> 6;           // 0..7
    const int wr = wv >> 2, wc = wv & 3;
    const size_t brow = (size_t)blockIdx.x * 128;

    const int ra = tid >> 2, ca = tid & 3;
    const int rb1 = ra + 128;
    const int csa = ca ^ ((ra >> 1) & 3);
    const ushort_t* gA  = A  + (brow + ra) * 256 + ca * 8;
    const ushort_t* gB0 = Wt + (size_t)ra  * 256 + ca * 8;
    const ushort_t* gB1 = Wt + (size_t)rb1 * 256 + ca * 8;
    ushort_t* lA  = As + ra * 32 + csa * 8;
    ushort_t* lB0 = Bs + ra * 32 + csa * 8;
    ushort_t* lB1 = Bs + rb1 * 32 + csa * 8;

    const int g = lane >> 4, rl = lane & 15;
    int aoff[4], boff[4];
    #pragma unroll
    for (int m = 0; m < 4; ++m) {
        int row = wr * 64 + m * 16 + rl;
        aoff[m] = row * 32 + (g ^ ((row >> 1) & 3)) * 8;
    }
    #pragma unroll
    for (int n = 0; n < 4; ++n) {
        int row = wc * 64 + n * 16 + rl;
        boff[n] = row * 32 + (g ^ ((row >> 1) & 3)) * 8;
    }

    if (MODE == 2 && tid < 128) s_t[tid] = 0.f;

    f32x4 acc[4][4] = {};
    uint4 va  = *(const uint4*)gA;
    uint4 vb0 = *(const uint4*)gB0;
    uint4 vb1 = *(const uint4*)gB1;

    for (int ks = 0; ks < 8; ++ks) {
        *(uint4*)lA = va; *(uint4*)lB0 = vb0; *(uint4*)lB1 = vb1;
        __syncthreads();
        if (ks < 7) {
            int k0 = (ks + 1) * 32;
            va  = *(const uint4*)(gA + k0);
            vb0 = *(const uint4*)(gB0 + k0);
            vb1 = *(const uint4*)(gB1 + k0);
        }
        short8 af[4], bfv[4];
        #pragma unroll
        for (int m = 0; m < 4; ++m) af[m] = *(const short8*)(As + aoff[m]);
        #pragma unroll
        for (int n = 0; n < 4; ++n) bfv[n] = *(const short8*)(Bs + boff[n]);
        #pragma unroll
        for (int m = 0; m < 4; ++m)
            #pragma unroll
            for (int n = 0; n < 4; ++n)
                acc[m][n] = __builtin_amdgcn_mfma_f32_16x16x32_bf16(
                    af[m], bfv[n], acc[m][n], 0, 0, 0);
        __syncthreads();
    }

    if (MODE == 2) {
        float uvv[4];
        #pragma unroll
        for (int n = 0; n < 4; ++n) uvv[n] = u[wc * 64 + n * 16 + rl];
        #pragma unroll
        for (int m = 0; m < 4; ++m) {
            #pragma unroll
            for (int r = 0; r < 4; ++r) {
                float v = 0.f;
                #pragma unroll
                for (int n = 0; n < 4; ++n) v += tanhf(acc[m][n][r]) * uvv[n];
                v += __shfl_xor(v, 1, 64);
                v += __shfl_xor(v, 2, 64);
                v += __shfl_xor(v, 4, 64);
                v += __shfl_xor(v, 8, 64);
                if (rl == 0) atomicAdd(&s_t[wr * 64 + m * 16 + g * 4 + r], v);
            }
        }
        __syncthreads();
        if (tid < 128 && brow + tid < (size_t)mvalid) tout[brow + tid] = s_t[tid];
    } else {
        #pragma unroll
        for (int m = 0; m < 4; ++m) {
            #pragma unroll
            for (int r = 0; r < 4; ++r) {
                size_t row = brow + wr * 64 + m * 16 + g * 4 + r;
                #pragma unroll
                for (int n = 0; n < 4; ++n) {
                    int col = wc * 64 + n * 16 + rl;
                    float v = acc[m][n][r] + bias[col];
                    if (MODE == 0) v = fmaxf(v, 0.f);
                    out[row * 256 + col] = f2bfu(v);
                }
            }
        }
    }
}

// ---------------- code attention: one block per (b,v), emb bf16 -> vemb bf16
__global__ __launch_bounds__(256) void code_attn_kernel(
    const int* __restrict__ codes, const float* __restrict__ t,
    const ushort_t* __restrict__ emb, ushort_t* __restrict__ vembB,
    int* __restrict__ vmask) {
    int bv = blockIdx.x;
    int tid = threadIdx.x;
    __shared__ int s_codes[CODES];
    __shared__ float s_av[CODES];
    __shared__ int s_valid;
    if (tid < 64) {
        int c = codes[(size_t)bv * CODES + tid];
        s_codes[tid] = c;
        float e = (c > 0) ? t[c] : NEG_INF;
        float m = e;
        #pragma unroll
        for (int d = 32; d; d >>= 1) m = fmaxf(m, __shfl_xor(m, d, 64));
        float ex = expf(e - m);
        float s = ex;
        #pragma unroll
        for (int d = 32; d; d >>= 1) s += __shfl_xor(s, d, 64);
        s_av[tid] = ex / s;
        if (tid == 0) s_valid = (m > -1e8f) ? 1 : 0;
    }
    __syncthreads();
    float acc = 0.f;
    #pragma unroll 4
    for (int c = 0; c < CODES; ++c) {
        int node = s_codes[c];
        if (node > 0) acc += s_av[c] * bf2f(emb[(size_t)node * D + tid]);
    }
    int valid = s_valid;
    vembB[(size_t)bv * D + tid] = f2bfu(valid ? acc : 0.f);
    if (tid == 0) vmask[bv] = valid;
}

// per-patient: masked softmax over visit scores, pemb = sum ap * vemb
__global__ __launch_bounds__(256) void patient_kernel(
    const ushort_t* __restrict__ vembB, const float* __restrict__ epr,
    const int* __restrict__ vmask, float* __restrict__ pemb) {
    int b = blockIdx.x;
    int tid = threadIdx.x;
    __shared__ float s_ap[VIS];
    __shared__ int s_any;
    if (tid < 64) {
        float e = -3e38f;
        if (tid < VIS) e = vmask[b * VIS + tid] ? epr[b * VIS + tid] : NEG_INF;
        float m = e;
        #pragma unroll
        for (int d = 32; d; d >>= 1) m = fmaxf(m, __shfl_xor(m, d, 64));
        float ex = (tid < VIS) ? expf(e - m) : 0.f;
        float s = ex;
        #pragma unroll
        for (int d = 32; d; d >>= 1) s += __shfl_xor(s, d, 64);
        if (tid < VIS) s_ap[tid] = ex / s;
        if (tid == 0) s_any = (m > -1e8f) ? 1 : 0;
    }
    __syncthreads();
    float acc = 0.f;
    for (int v = 0; v < VIS; ++v)
        acc += s_ap[v] * bf2f(vembB[((size_t)b * VIS + v) * D + tid]);
    pemb[b * D + tid] = s_any ? acc : 0.f;
}

__global__ __launch_bounds__(256) void gemm_rowcol(
    const float* __restrict__ A, const float* __restrict__ W,
    const float* __restrict__ bias, float* __restrict__ C,
    int M, int N, int K, int act) {
    int row = blockIdx.x;
    int col = blockIdx.y * 256 + threadIdx.x;
    if (col >= N) return;
    const float* a = A + (size_t)row * K;
    float acc = bias ? bias[col] : 0.f;
    #pragma unroll 4
    for (int k = 0; k < K; ++k) acc = fmaf(a[k], W[(size_t)k * N + col], acc);
    if (act == 1) acc = fmaxf(acc, 0.f);
    C[(size_t)row * N + col] = acc;
}

extern "C" void kernel_launch(void* const* d_in, const int* in_sizes, int n_in,
                              void* d_out, int out_size, void* d_ws, size_t ws_size,
                              hipStream_t stream) {
    const int* edge_index    = (const int*)d_in[0];
    const float* edge_weight = (const float*)d_in[1];
    const int* codes         = (const int*)d_in[2];
    const float* node_emb    = (const float*)d_in[3];
    const float* W1 = (const float*)d_in[4];
    const float* b1 = (const float*)d_in[5];
    const float* W2 = (const float*)d_in[6];
    const float* b2 = (const float*)d_in[7];
    const float* Wv = (const float*)d_in[8];
    const float* uv = (const float*)d_in[9];
    const float* Wp = (const float*)d_in[10];
    const float* up = (const float*)d_in[11];
    const float* Wd1 = (const float*)d_in[12];
    const float* bd1 = (const float*)d_in[13];
    const float* Wd2 = (const float*)d_in[14];
    const float* bd2 = (const float*)d_in[15];
    const float* Wd3 = (const float*)d_in[16];
    const float* bd3 = (const float*)d_in[17];

    const int NE = in_sizes[1];          // 3,200,000
    const int NN = in_sizes[3] / D;      // 100,000

    char* ws = (char*)d_ws;
    size_t off = 0;
    auto alloc = [&](size_t bytes) -> void* {
        void* p = ws + off;
        off += (bytes + 255) & ~(size_t)255;
        return p;
    };
    ushort_t* nbf  = (ushort_t*)alloc((size_t)MPAD * D * 2);  // node table / h
    ushort_t* aggb = (ushort_t*)alloc((size_t)MPAD * D * 2);  // agg out
    ushort_t* embB = (ushort_t*)alloc((size_t)MPAD * D * 2);  // emb (bf16)
    uint2* pairs  = (uint2*)alloc((size_t)NE * 8);            // binned (key,w)
    int* bincount = (int*)alloc((size_t)NBIN * 4);
    int* binstart = (int*)alloc((size_t)NBIN * 4);
    int* bincursor= (int*)alloc((size_t)NBIN * 4);
    ushort_t* W1t = (ushort_t*)alloc(256 * 256 * 2);
    ushort_t* W2t = (ushort_t*)alloc(256 * 256 * 2);
    ushort_t* Wvt = (ushort_t*)alloc(256 * 256 * 2);
    ushort_t* Wpt = (ushort_t*)alloc(256 * 256 * 2);
    float* tbuf  = (float*)alloc((size_t)NN * 4);
    ushort_t* vembB = (ushort_t*)alloc((size_t)BPAT * VIS * D * 2);
    int*   vmask = (int*)  alloc((size_t)BPAT * VIS * 4);
    float* epr   = (float*)alloc((size_t)BPAT * VIS * 4);
    float* pemb  = (float*)alloc((size_t)BPAT * D * 4);
    float* h1    = (float*)alloc((size_t)BPAT * 512 * 4);
    float* h2    = (float*)alloc((size_t)BPAT * D * 4);
    (void)ws_size; (void)n_in; (void)out_size;

    // --- binned edge partition (replaces hist/scan/fill CSR build) ---
    hipMemsetAsync(bincount, 0, (size_t)NBIN * 4, stream);
    bin_count_kernel<<<256, 512, 0, stream>>>(edge_index, bincount, NE);
    bin_scan_kernel<<<1, 64, 0, stream>>>(bincount, binstart, bincursor);
    partition_kernel<<<256, 512, 0, stream>>>(edge_index, edge_weight,
                                              bincursor, pairs, NE);

    // --- bf16 conversions ---
    cvt_node_kernel<<<2048, 256, 0, stream>>>(node_emb, nbf, (long)NN * D, (long)MPAD * D);
    dim3 tg(8, 8);
    transpose_w_kernel<<<tg, 256, 0, stream>>>(W1, W1t);
    transpose_w_kernel<<<tg, 256, 0, stream>>>(W2, W2t);
    transpose_w_kernel<<<tg, 256, 0, stream>>>(Wv, Wvt);
    transpose_w_kernel<<<tg, 256, 0, stream>>>(Wp, Wpt);

    // --- GCN layer 1: h = relu(agg(x) @ W1 + b1) ---
    agg_bin_kernel<<<NBIN, 256, 0, stream>>>(nbf, binstart, bincount, pairs, aggb, NN);
    mfma_gemm_kernel<0><<<MPAD / 128, 512, 0, stream>>>(
        aggb, W1t, b1, nbf, nullptr, nullptr, 0);

    // --- GCN layer 2: emb = agg(h) @ W2 + b2 ---
    agg_bin_kernel<<<NBIN, 256, 0, stream>>>(nbf, binstart, bincount, pairs, aggb, NN);
    mfma_gemm_kernel<1><<<MPAD / 128, 512, 0, stream>>>(
        aggb, W2t, b2, embB, nullptr, nullptr, 0);

    // --- fused per-node code score: t = tanh(emb @ Wv) @ uv ---
    mfma_gemm_kernel<2><<<MPAD / 128, 512, 0, stream>>>(
        embB, Wvt, nullptr, nullptr, uv, tbuf, NN);

    // --- code attention -> vemb (bf16) ---
    code_attn_kernel<<<BPAT * VIS, 256, 0, stream>>>(codes, tbuf, embB, vembB, vmask);

    // --- fused visit score: ep = tanh(vemb @ Wp) @ up  (3200 = 25*128 rows) ---
    mfma_gemm_kernel<2><<<BPAT * VIS / 128, 512, 0, stream>>>(
        vembB, Wpt, nullptr, nullptr, up, epr, BPAT * VIS);

    // --- patient attention + decoder ---
    patient_kernel<<<BPAT, 256, 0, stream>>>(vembB, epr, vmask, pemb);
    gemm_rowcol<<<dim3(BPAT, 2), 256, 0, stream>>>(pemb, Wd1, bd1, h1, BPAT, 512, D, 1);
    gemm_rowcol<<<dim3(BPAT, 1), 256, 0, stream>>>(h1, Wd2, bd2, h2, BPAT, D, 512, 1);
    gemm_rowcol<<<dim3(BPAT, 4), 256, 0, stream>>>(h2, Wd3, bd3, (float*)d_out, BPAT, 1000, D, 0);
}

// Round 8
// 924.407 us; speedup vs baseline: 1.3118x; 1.3118x over previous
//
#include <hip/hip_runtime.h>
#include <hip/hip_bf16.h>
#include <math.h>

// DualMAR: 2-layer weighted GCN over 100K nodes / 3.2M edges + code/visit
// attention + MLP decoder.
// R7: best-of-R4+R6. Binned partition (cheap, no random-scatter wall) +
// NEW binsort pass (block per 32-dst bin: LDS count -> scan -> cursor
// scatter) produces a fully dst-sorted (src,w) CSR; the proven R4
// per-dst-wave agg_bf16 (231us, 3.6 TB/s) consumes it. R6's slow
// shfl-broadcast agg_bin is dropped. GEMM/attention unchanged.

#define D 256
#define BPAT 64
#define VIS 50
#define CODES 64
#define NEG_INF -1e9f
#define MPAD 100096   // 782 * 128 (NN=100000 padded to BM=128)
#define BINB 32       // dsts per bin
#define NBIN 3125     // 3125 * 32 = 100000 exactly

typedef unsigned short ushort_t;
typedef short short8 __attribute__((ext_vector_type(8)));
typedef float f32x4 __attribute__((ext_vector_type(4)));

__device__ __forceinline__ float blo(unsigned u) { return __uint_as_float(u << 16); }
__device__ __forceinline__ float bhi(unsigned u) { return __uint_as_float(u & 0xffff0000u); }
__device__ __forceinline__ float bf2f(ushort_t u) { return __uint_as_float((unsigned)u << 16); }
__device__ __forceinline__ ushort_t f2bfu(float f) {
    __hip_bfloat16 h = __float2bfloat16(f);
    return *reinterpret_cast<ushort_t*>(&h);
}
__device__ __forceinline__ unsigned pack2(float a, float b) {
    return (unsigned)f2bfu(a) | ((unsigned)f2bfu(b) << 16);
}

// ---------------- binned edge partition ----------------

// P1: per-bin edge counts (LDS-aggregated histogram)
__global__ __launch_bounds__(512) void bin_count_kernel(
    const int* __restrict__ ei, int* __restrict__ bincount, int ne) {
    __shared__ int h[NBIN];
    for (int i = threadIdx.x; i < NBIN; i += 512) h[i] = 0;
    __syncthreads();
    int stride = gridDim.x * 512;
    for (int e = blockIdx.x * 512 + threadIdx.x; e < ne; e += stride)
        atomicAdd(&h[ei[(size_t)ne + e] >> 5], 1);
    __syncthreads();
    for (int i = threadIdx.x; i < NBIN; i += 512) {
        int c = h[i];
        if (c) atomicAdd(&bincount[i], c);
    }
}

// P2: exclusive scan -> binstart[0..NBIN], bincursor; also rp[nn]=ne
__global__ __launch_bounds__(64) void bin_scan_kernel(
    const int* __restrict__ bincount, int* __restrict__ binstart,
    int* __restrict__ bincursor, int* __restrict__ rp, int ne, int nn) {
    __shared__ int carry;
    int lane = threadIdx.x;
    if (lane == 0) carry = 0;
    __syncthreads();
    for (int base = 0; base < NBIN; base += 64) {
        int i = base + lane;
        int v = (i < NBIN) ? bincount[i] : 0;
        int x = v;
        #pragma unroll
        for (int d = 1; d < 64; d <<= 1) {
            int y = __shfl_up(x, (unsigned)d, 64);
            if (lane >= d) x += y;
        }
        int c = carry;
        if (i < NBIN) { int ex = c + x - v; binstart[i] = ex; bincursor[i] = ex; }
        __syncthreads();
        if (lane == 63) carry = c + x;
        __syncthreads();
    }
    if (lane == 0) { binstart[NBIN] = ne; rp[nn] = ne; }
}

// P3: partition edges into bin-contiguous (key,w); key = src | (dst&31)<<17.
// One reserve atomic per (block,bin); LDS-ranked 64B-run writes.
__global__ __launch_bounds__(512) void partition_kernel(
    const int* __restrict__ ei, const float* __restrict__ ew,
    int* __restrict__ bincursor, uint2* __restrict__ ptmp, int ne) {
    __shared__ int h[NBIN];
    __shared__ int base_[NBIN];
    for (int i = threadIdx.x; i < NBIN; i += 512) h[i] = 0;
    __syncthreads();
    int stride = gridDim.x * 512;
    for (int e = blockIdx.x * 512 + threadIdx.x; e < ne; e += stride)
        atomicAdd(&h[ei[(size_t)ne + e] >> 5], 1);
    __syncthreads();
    for (int i = threadIdx.x; i < NBIN; i += 512) {
        int c = h[i];
        base_[i] = c ? atomicAdd(&bincursor[i], c) : 0;
        h[i] = 0;
    }
    __syncthreads();
    for (int e = blockIdx.x * 512 + threadIdx.x; e < ne; e += stride) {
        int dd = ei[(size_t)ne + e];
        int ss = ei[e];
        float w = ew[e];
        int bin = dd >> 5;
        int r = atomicAdd(&h[bin], 1);
        ptmp[base_[bin] + r] =
            make_uint2((unsigned)ss | ((unsigned)(dd & 31) << 17),
                       __float_as_uint(w));
    }
}

// P4: within-bin counting sort -> fully dst-sorted (src,w) + rp[] CSR.
// One block per bin; all reads/writes stay inside the bin's ~8KB region.
__global__ __launch_bounds__(256) void binsort_kernel(
    const uint2* __restrict__ ptmp, const int* __restrict__ binstart,
    uint2* __restrict__ epair, int* __restrict__ rp) {
    int b = blockIdx.x;
    int tid = threadIdx.x;
    int beg = binstart[b], end = binstart[b + 1];
    __shared__ int cnt[BINB];
    __shared__ int cur[BINB];
    if (tid < BINB) cnt[tid] = 0;
    __syncthreads();
    for (int i = beg + tid; i < end; i += 256)
        atomicAdd(&cnt[(ptmp[i].x >> 17) & 31], 1);
    __syncthreads();
    if (tid < BINB) {                  // lanes 0..31 of wave 0: width-32 scan
        int v = cnt[tid];
        int x = v;
        #pragma unroll
        for (int d = 1; d < BINB; d <<= 1) {
            int y = __shfl_up(x, (unsigned)d, BINB);
            if (tid >= d) x += y;
        }
        int start = beg + x - v;       // exclusive prefix within bin
        cur[tid] = start;
        rp[b * BINB + tid] = start;
    }
    __syncthreads();
    for (int i = beg + tid; i < end; i += 256) {
        uint2 p = ptmp[i];
        int dl = (p.x >> 17) & 31;
        int pos = atomicAdd(&cur[dl], 1);
        epair[pos] = make_uint2(p.x & 0x1FFFF, p.y);
    }
}

// ---------------- fp32 -> bf16 node table (pad rows zeroed) ----------------
__global__ void cvt_node_kernel(const float* __restrict__ in, ushort_t* __restrict__ out,
                                long n_valid, long n_total) {
    long g = (long)blockIdx.x * blockDim.x + threadIdx.x;
    long ng = n_total >> 2;
    for (long i = g; i < ng; i += (long)gridDim.x * blockDim.x) {
        long e = i << 2;
        uint2 o;
        if (e < n_valid) {
            float4 v = ((const float4*)in)[i];
            o.x = pack2(v.x, v.y);
            o.y = pack2(v.z, v.w);
        } else {
            o.x = 0u; o.y = 0u;
        }
        ((uint2*)out)[i] = o;
    }
}

// ---------------- weight transpose: W[k][n] fp32 -> Wt[n][k] bf16 (256x256) --
__global__ __launch_bounds__(256) void transpose_w_kernel(
    const float* __restrict__ W, ushort_t* __restrict__ Wt) {
    __shared__ float t[32][33];
    int bx = blockIdx.x * 32;   // n base
    int by = blockIdx.y * 32;   // k base
    int lx = threadIdx.x & 31, ly = threadIdx.x >> 5;   // 32 x 8
    #pragma unroll
    for (int i = 0; i < 32; i += 8)
        t[ly + i][lx] = W[(size_t)(by + ly + i) * 256 + bx + lx];
    __syncthreads();
    #pragma unroll
    for (int i = 0; i < 32; i += 8)
        Wt[(size_t)(bx + ly + i) * 256 + by + lx] = f2bfu(t[lx][ly + i]);
}

// ---------------- weighted aggregation over bf16 rows (R4-proven) ----------
// One wave per dst row, two 32-lane halves gather different edges with
// 16B/lane uint4 loads; 8-edge unrolled main loop.
__device__ __forceinline__ void acc8(float* a, uint4 v, float w) {
    a[0] += w * blo(v.x); a[1] += w * bhi(v.x);
    a[2] += w * blo(v.y); a[3] += w * bhi(v.y);
    a[4] += w * blo(v.z); a[5] += w * bhi(v.z);
    a[6] += w * blo(v.w); a[7] += w * bhi(v.w);
}

__global__ __launch_bounds__(256) void agg_bf16_kernel(
    const ushort_t* __restrict__ x, const int* __restrict__ rp,
    const uint2* __restrict__ ep, ushort_t* __restrict__ out, int n) {
    int wv = (int)(((size_t)blockIdx.x * blockDim.x + threadIdx.x) >> 6);
    int lane = threadIdx.x & 63;
    if (wv >= n) return;
    int half = lane >> 5;
    int l32 = lane & 31;
    int beg = rp[wv], end = rp[wv + 1];
    float a[8] = {};
    int e = beg;
    for (; e + 8 <= end; e += 8) {
        uint2 p0 = ep[e + half];
        uint2 p1 = ep[e + 2 + half];
        uint2 p2 = ep[e + 4 + half];
        uint2 p3 = ep[e + 6 + half];
        uint4 v0 = ((const uint4*)(x + (size_t)p0.x * D))[l32];
        uint4 v1 = ((const uint4*)(x + (size_t)p1.x * D))[l32];
        uint4 v2 = ((const uint4*)(x + (size_t)p2.x * D))[l32];
        uint4 v3 = ((const uint4*)(x + (size_t)p3.x * D))[l32];
        acc8(a, v0, __uint_as_float(p0.y));
        acc8(a, v1, __uint_as_float(p1.y));
        acc8(a, v2, __uint_as_float(p2.y));
        acc8(a, v3, __uint_as_float(p3.y));
    }
    for (; e + 2 <= end; e += 2) {
        uint2 p0 = ep[e + half];
        uint4 v0 = ((const uint4*)(x + (size_t)p0.x * D))[l32];
        acc8(a, v0, __uint_as_float(p0.y));
    }
    if (e < end) {   // odd tail: both halves read the same row, upper weight 0
        uint2 p0 = ep[e];
        uint4 v0 = ((const uint4*)(x + (size_t)p0.x * D))[l32];
        acc8(a, v0, half ? 0.f : __uint_as_float(p0.y));
    }
    #pragma unroll
    for (int j = 0; j < 8; ++j) a[j] += __shfl_xor(a[j], 32, 64);
    if (half == 0) {
        uint4 o;
        o.x = pack2(a[0], a[1]); o.y = pack2(a[2], a[3]);
        o.z = pack2(a[4], a[5]); o.w = pack2(a[6], a[7]);
        ((uint4*)(out + (size_t)wv * D))[l32] = o;
    }
}

// ---------------- bf16 MFMA GEMM: 128x256 tile, BK=32, 8 waves (512 thr) ----
// A bf16 row-major [*,256]; Wt = W^T bf16. LDS XOR-swizzle c^=((row>>1)&3).
// MODE 0: relu(A@W+bias) -> bf16 out
// MODE 1: A@W+bias       -> bf16 out
// MODE 2: tout[row] = sum_col tanh((A@W)[row,col]) * u[col]  (no out store)
template<int MODE>
__global__ __launch_bounds__(512) void mfma_gemm_kernel(
    const ushort_t* __restrict__ A, const ushort_t* __restrict__ Wt,
    const float* __restrict__ bias, ushort_t* __restrict__ out,
    const float* __restrict__ u, float* __restrict__ tout, int mvalid) {
    __shared__ __align__(16) ushort_t As[128 * 32];
    __shared__ __align__(16) ushort_t Bs[256 * 32];
    __shared__ float s_t[128];
    const int tid = threadIdx.x;
    const int lane = tid & 63;
    const int wv = tid >> 6;           // 0..7
    const int wr = wv >> 2, wc = wv & 3;
    const size_t brow = (size_t)blockIdx.x * 128;

    const int ra = tid >> 2, ca = tid & 3;
    const int rb1 = ra + 128;
    const int csa = ca ^ ((ra >> 1) & 3);
    const ushort_t* gA  = A  + (brow + ra) * 256 + ca * 8;
    const ushort_t* gB0 = Wt + (size_t)ra  * 256 + ca * 8;
    const ushort_t* gB1 = Wt + (size_t)rb1 * 256 + ca * 8;
    ushort_t* lA  = As + ra * 32 + csa * 8;
    ushort_t* lB0 = Bs + ra * 32 + csa * 8;
    ushort_t* lB1 = Bs + rb1 * 32 + csa * 8;

    const int g = lane >> 4, rl = lane & 15;
    int aoff[4], boff[4];
    #pragma unroll
    for (int m = 0; m < 4; ++m) {
        int row = wr * 64 + m * 16 + rl;
        aoff[m] = row * 32 + (g ^ ((row >> 1) & 3)) * 8;
    }
    #pragma unroll
    for (int n = 0; n < 4; ++n) {
        int row = wc * 64 + n * 16 + rl;
        boff[n] = row * 32 + (g ^ ((row >> 1) & 3)) * 8;
    }

    if (MODE == 2 && tid < 128) s_t[tid] = 0.f;

    f32x4 acc[4][4] = {};
    uint4 va  = *(const uint4*)gA;
    uint4 vb0 = *(const uint4*)gB0;
    uint4 vb1 = *(const uint4*)gB1;

    for (int ks = 0; ks < 8; ++ks) {
        *(uint4*)lA = va; *(uint4*)lB0 = vb0; *(uint4*)lB1 = vb1;
        __syncthreads();
        if (ks < 7) {
            int k0 = (ks + 1) * 32;
            va  = *(const uint4*)(gA + k0);
            vb0 = *(const uint4*)(gB0 + k0);
            vb1 = *(const uint4*)(gB1 + k0);
        }
        short8 af[4], bfv[4];
        #pragma unroll
        for (int m = 0; m < 4; ++m) af[m] = *(const short8*)(As + aoff[m]);
        #pragma unroll
        for (int n = 0; n < 4; ++n) bfv[n] = *(const short8*)(Bs + boff[n]);
        #pragma unroll
        for (int m = 0; m < 4; ++m)
            #pragma unroll
            for (int n = 0; n < 4; ++n)
                acc[m][n] = __builtin_amdgcn_mfma_f32_16x16x32_bf16(
                    af[m], bfv[n], acc[m][n], 0, 0, 0);
        __syncthreads();
    }

    if (MODE == 2) {
        float uvv[4];
        #pragma unroll
        for (int n = 0; n < 4; ++n) uvv[n] = u[wc * 64 + n * 16 + rl];
        #pragma unroll
        for (int m = 0; m < 4; ++m) {
            #pragma unroll
            for (int r = 0; r < 4; ++r) {
                float v = 0.f;
                #pragma unroll
                for (int n = 0; n < 4; ++n) v += tanhf(acc[m][n][r]) * uvv[n];
                v += __shfl_xor(v, 1, 64);
                v += __shfl_xor(v, 2, 64);
                v += __shfl_xor(v, 4, 64);
                v += __shfl_xor(v, 8, 64);
                if (rl == 0) atomicAdd(&s_t[wr * 64 + m * 16 + g * 4 + r], v);
            }
        }
        __syncthreads();
        if (tid < 128 && brow + tid < (size_t)mvalid) tout[brow + tid] = s_t[tid];
    } else {
        #pragma unroll
        for (int m = 0; m < 4; ++m) {
            #pragma unroll
            for (int r = 0; r < 4; ++r) {
                size_t row = brow + wr * 64 + m * 16 + g * 4 + r;
                #pragma unroll
                for (int n = 0; n < 4; ++n) {
                    int col = wc * 64 + n * 16 + rl;
                    float v = acc[m][n][r] + bias[col];
                    if (MODE == 0) v = fmaxf(v, 0.f);
                    out[row * 256 + col] = f2bfu(v);
                }
            }
        }
    }
}

// ---------------- code attention: one block per (b,v), emb bf16 -> vemb bf16
__global__ __launch_bounds__(256) void code_attn_kernel(
    const int* __restrict__ codes, const float* __restrict__ t,
    const ushort_t* __restrict__ emb, ushort_t* __restrict__ vembB,
    int* __restrict__ vmask) {
    int bv = blockIdx.x;
    int tid = threadIdx.x;
    __shared__ int s_codes[CODES];
    __shared__ float s_av[CODES];
    __shared__ int s_valid;
    if (tid < 64) {
        int c = codes[(size_t)bv * CODES + tid];
        s_codes[tid] = c;
        float e = (c > 0) ? t[c] : NEG_INF;
        float m = e;
        #pragma unroll
        for (int d = 32; d; d >>= 1) m = fmaxf(m, __shfl_xor(m, d, 64));
        float ex = expf(e - m);
        float s = ex;
        #pragma unroll
        for (int d = 32; d; d >>= 1) s += __shfl_xor(s, d, 64);
        s_av[tid] = ex / s;
        if (tid == 0) s_valid = (m > -1e8f) ? 1 : 0;
    }
    __syncthreads();
    float acc = 0.f;
    #pragma unroll 4
    for (int c = 0; c < CODES; ++c) {
        int node = s_codes[c];
        if (node > 0) acc += s_av[c] * bf2f(emb[(size_t)node * D + tid]);
    }
    int valid = s_valid;
    vembB[(size_t)bv * D + tid] = f2bfu(valid ? acc : 0.f);
    if (tid == 0) vmask[bv] = valid;
}

// per-patient: masked softmax over visit scores, pemb = sum ap * vemb
__global__ __launch_bounds__(256) void patient_kernel(
    const ushort_t* __restrict__ vembB, const float* __restrict__ epr,
    const int* __restrict__ vmask, float* __restrict__ pemb) {
    int b = blockIdx.x;
    int tid = threadIdx.x;
    __shared__ float s_ap[VIS];
    __shared__ int s_any;
    if (tid < 64) {
        float e = -3e38f;
        if (tid < VIS) e = vmask[b * VIS + tid] ? epr[b * VIS + tid] : NEG_INF;
        float m = e;
        #pragma unroll
        for (int d = 32; d; d >>= 1) m = fmaxf(m, __shfl_xor(m, d, 64));
        float ex = (tid < VIS) ? expf(e - m) : 0.f;
        float s = ex;
        #pragma unroll
        for (int d = 32; d; d >>= 1) s += __shfl_xor(s, d, 64);
        if (tid < VIS) s_ap[tid] = ex / s;
        if (tid == 0) s_any = (m > -1e8f) ? 1 : 0;
    }
    __syncthreads();
    float acc = 0.f;
    for (int v = 0; v < VIS; ++v)
        acc += s_ap[v] * bf2f(vembB[((size_t)b * VIS + v) * D + tid]);
    pemb[b * D + tid] = s_any ? acc : 0.f;
}

__global__ __launch_bounds__(256) void gemm_rowcol(
    const float* __restrict__ A, const float* __restrict__ W,
    const float* __restrict__ bias, float* __restrict__ C,
    int M, int N, int K, int act) {
    int row = blockIdx.x;
    int col = blockIdx.y * 256 + threadIdx.x;
    if (col >= N) return;
    const float* a = A + (size_t)row * K;
    float acc = bias ? bias[col] : 0.f;
    #pragma unroll 4
    for (int k = 0; k < K; ++k) acc = fmaf(a[k], W[(size_t)k * N + col], acc);
    if (act == 1) acc = fmaxf(acc, 0.f);
    C[(size_t)row * N + col] = acc;
}

extern "C" void kernel_launch(void* const* d_in, const int* in_sizes, int n_in,
                              void* d_out, int out_size, void* d_ws, size_t ws_size,
                              hipStream_t stream) {
    const int* edge_index    = (const int*)d_in[0];
    const float* edge_weight = (const float*)d_in[1];
    const int* codes         = (const int*)d_in[2];
    const float* node_emb    = (const float*)d_in[3];
    const float* W1 = (const float*)d_in[4];
    const float* b1 = (const float*)d_in[5];
    const float* W2 = (const float*)d_in[6];
    const float* b2 = (const float*)d_in[7];
    const float* Wv = (const float*)d_in[8];
    const float* uv = (const float*)d_in[9];
    const float* Wp = (const float*)d_in[10];
    const float* up = (const float*)d_in[11];
    const float* Wd1 = (const float*)d_in[12];
    const float* bd1 = (const float*)d_in[13];
    const float* Wd2 = (const float*)d_in[14];
    const float* bd2 = (const float*)d_in[15];
    const float* Wd3 = (const float*)d_in[16];
    const float* bd3 = (const float*)d_in[17];

    const int NE = in_sizes[1];          // 3,200,000
    const int NN = in_sizes[3] / D;      // 100,000

    char* ws = (char*)d_ws;
    size_t off = 0;
    auto alloc = [&](size_t bytes) -> void* {
        void* p = ws + off;
        off += (bytes + 255) & ~(size_t)255;
        return p;
    };
    ushort_t* nbf  = (ushort_t*)alloc((size_t)MPAD * D * 2);  // node table / h
    ushort_t* aggb = (ushort_t*)alloc((size_t)MPAD * D * 2);  // agg out
    ushort_t* embB = (ushort_t*)alloc((size_t)MPAD * D * 2);  // emb (bf16)
    uint2* ptmp   = (uint2*)alloc((size_t)NE * 8);            // bin-partitioned
    uint2* epair  = (uint2*)alloc((size_t)NE * 8);            // dst-sorted (src,w)
    int* bincount = (int*)alloc((size_t)NBIN * 4);
    int* binstart = (int*)alloc((size_t)(NBIN + 1) * 4);
    int* bincursor= (int*)alloc((size_t)NBIN * 4);
    int* rp       = (int*)alloc((size_t)(NN + 1) * 4);
    ushort_t* W1t = (ushort_t*)alloc(256 * 256 * 2);
    ushort_t* W2t = (ushort_t*)alloc(256 * 256 * 2);
    ushort_t* Wvt = (ushort_t*)alloc(256 * 256 * 2);
    ushort_t* Wpt = (ushort_t*)alloc(256 * 256 * 2);
    float* tbuf  = (float*)alloc((size_t)NN * 4);
    ushort_t* vembB = (ushort_t*)alloc((size_t)BPAT * VIS * D * 2);
    int*   vmask = (int*)  alloc((size_t)BPAT * VIS * 4);
    float* epr   = (float*)alloc((size_t)BPAT * VIS * 4);
    float* pemb  = (float*)alloc((size_t)BPAT * D * 4);
    float* h1    = (float*)alloc((size_t)BPAT * 512 * 4);
    float* h2    = (float*)alloc((size_t)BPAT * D * 4);
    (void)ws_size; (void)n_in; (void)out_size;

    const int ab = NN / 4;                    // one wave/row, 4 waves/block

    // --- binned partition + within-bin sort -> dst-sorted CSR ---
    hipMemsetAsync(bincount, 0, (size_t)NBIN * 4, stream);
    bin_count_kernel<<<256, 512, 0, stream>>>(edge_index, bincount, NE);
    bin_scan_kernel<<<1, 64, 0, stream>>>(bincount, binstart, bincursor, rp, NE, NN);
    partition_kernel<<<128, 512, 0, stream>>>(edge_index, edge_weight,
                                              bincursor, ptmp, NE);
    binsort_kernel<<<NBIN, 256, 0, stream>>>(ptmp, binstart, epair, rp);

    // --- bf16 conversions ---
    cvt_node_kernel<<<2048, 256, 0, stream>>>(node_emb, nbf, (long)NN * D, (long)MPAD * D);
    dim3 tg(8, 8);
    transpose_w_kernel<<<tg, 256, 0, stream>>>(W1, W1t);
    transpose_w_kernel<<<tg, 256, 0, stream>>>(W2, W2t);
    transpose_w_kernel<<<tg, 256, 0, stream>>>(Wv, Wvt);
    transpose_w_kernel<<<tg, 256, 0, stream>>>(Wp, Wpt);

    // --- GCN layer 1: h = relu(agg(x) @ W1 + b1) ---
    agg_bf16_kernel<<<ab, 256, 0, stream>>>(nbf, rp, epair, aggb, NN);
    mfma_gemm_kernel<0><<<MPAD / 128, 512, 0, stream>>>(
        aggb, W1t, b1, nbf, nullptr, nullptr, 0);

    // --- GCN layer 2: emb = agg(h) @ W2 + b2 ---
    agg_bf16_kernel<<<ab, 256, 0, stream>>>(nbf, rp, epair, aggb, NN);
    mfma_gemm_kernel<1><<<MPAD / 128, 512, 0, stream>>>(
        aggb, W2t, b2, embB, nullptr, nullptr, 0);

    // --- fused per-node code score: t = tanh(emb @ Wv) @ uv ---
    mfma_gemm_kernel<2><<<MPAD / 128, 512, 0, stream>>>(
        embB, Wvt, nullptr, nullptr, uv, tbuf, NN);

    // --- code attention -> vemb (bf16) ---
    code_attn_kernel<<<BPAT * VIS, 256, 0, stream>>>(codes, tbuf, embB, vembB, vmask);

    // --- fused visit score: ep = tanh(vemb @ Wp) @ up  (3200 = 25*128 rows) ---
    mfma_gemm_kernel<2><<<BPAT * VIS / 128, 512, 0, stream>>>(
        vembB, Wpt, nullptr, nullptr, up, epr, BPAT * VIS);

    // --- patient attention + decoder ---
    patient_kernel<<<BPAT, 256, 0, stream>>>(vembB, epr, vmask, pemb);
    gemm_rowcol<<<dim3(BPAT, 2), 256, 0, stream>>>(pemb, Wd1, bd1, h1, BPAT, 512, D, 1);
    gemm_rowcol<<<dim3(BPAT, 1), 256, 0, stream>>>(h1, Wd2, bd2, h2, BPAT, D, 512, 1);
    gemm_rowcol<<<dim3(BPAT, 4), 256, 0, stream>>>(h2, Wd3, bd3, (float*)d_out, BPAT, 1000, D, 0);
}

// Round 9
// 911.121 us; speedup vs baseline: 1.3309x; 1.0146x over previous
//
#include <hip/hip_runtime.h>
#include <hip/hip_bf16.h>
#include <math.h>

// DualMAR: 2-layer weighted GCN over 100K nodes / 3.2M edges + code/visit
// attention + MLP decoder.
// R8: agg 16-edge unroll (8 x 512B gathers in flight per wave; R7 had 4),
// binsort LDS-staged single-read (12KB buffer + global fallback), weight
// transposes fused into one launch. Pipeline otherwise identical to R7
// (binned partition -> binsort CSR -> per-dst-wave gather agg -> MFMA GEMMs
// with fused tanh-dot epilogues -> attention -> decoder).

#define D 256
#define BPAT 64
#define VIS 50
#define CODES 64
#define NEG_INF -1e9f
#define MPAD 100096   // 782 * 128 (NN=100000 padded to BM=128)
#define BINB 32       // dsts per bin
#define NBIN 3125     // 3125 * 32 = 100000 exactly
#define SORTCAP 1536  // LDS staging capacity in binsort (bin avg 1024)

typedef unsigned short ushort_t;
typedef short short8 __attribute__((ext_vector_type(8)));
typedef float f32x4 __attribute__((ext_vector_type(4)));

__device__ __forceinline__ float blo(unsigned u) { return __uint_as_float(u << 16); }
__device__ __forceinline__ float bhi(unsigned u) { return __uint_as_float(u & 0xffff0000u); }
__device__ __forceinline__ float bf2f(ushort_t u) { return __uint_as_float((unsigned)u << 16); }
__device__ __forceinline__ ushort_t f2bfu(float f) {
    __hip_bfloat16 h = __float2bfloat16(f);
    return *reinterpret_cast<ushort_t*>(&h);
}
__device__ __forceinline__ unsigned pack2(float a, float b) {
    return (unsigned)f2bfu(a) | ((unsigned)f2bfu(b) << 16);
}

// ---------------- binned edge partition ----------------

// P1: per-bin edge counts (LDS-aggregated histogram)
__global__ __launch_bounds__(512) void bin_count_kernel(
    const int* __restrict__ ei, int* __restrict__ bincount, int ne) {
    __shared__ int h[NBIN];
    for (int i = threadIdx.x; i < NBIN; i += 512) h[i] = 0;
    __syncthreads();
    int stride = gridDim.x * 512;
    for (int e = blockIdx.x * 512 + threadIdx.x; e < ne; e += stride)
        atomicAdd(&h[ei[(size_t)ne + e] >> 5], 1);
    __syncthreads();
    for (int i = threadIdx.x; i < NBIN; i += 512) {
        int c = h[i];
        if (c) atomicAdd(&bincount[i], c);
    }
}

// P2: exclusive scan -> binstart[0..NBIN], bincursor; also rp[nn]=ne
__global__ __launch_bounds__(64) void bin_scan_kernel(
    const int* __restrict__ bincount, int* __restrict__ binstart,
    int* __restrict__ bincursor, int* __restrict__ rp, int ne, int nn) {
    __shared__ int carry;
    int lane = threadIdx.x;
    if (lane == 0) carry = 0;
    __syncthreads();
    for (int base = 0; base < NBIN; base += 64) {
        int i = base + lane;
        int v = (i < NBIN) ? bincount[i] : 0;
        int x = v;
        #pragma unroll
        for (int d = 1; d < 64; d <<= 1) {
            int y = __shfl_up(x, (unsigned)d, 64);
            if (lane >= d) x += y;
        }
        int c = carry;
        if (i < NBIN) { int ex = c + x - v; binstart[i] = ex; bincursor[i] = ex; }
        __syncthreads();
        if (lane == 63) carry = c + x;
        __syncthreads();
    }
    if (lane == 0) { binstart[NBIN] = ne; rp[nn] = ne; }
}

// P3: partition edges into bin-contiguous (key,w); key = src | (dst&31)<<17.
// One reserve atomic per (block,bin); LDS-ranked writes.
__global__ __launch_bounds__(512) void partition_kernel(
    const int* __restrict__ ei, const float* __restrict__ ew,
    int* __restrict__ bincursor, uint2* __restrict__ ptmp, int ne) {
    __shared__ int h[NBIN];
    __shared__ int base_[NBIN];
    for (int i = threadIdx.x; i < NBIN; i += 512) h[i] = 0;
    __syncthreads();
    int stride = gridDim.x * 512;
    for (int e = blockIdx.x * 512 + threadIdx.x; e < ne; e += stride)
        atomicAdd(&h[ei[(size_t)ne + e] >> 5], 1);
    __syncthreads();
    for (int i = threadIdx.x; i < NBIN; i += 512) {
        int c = h[i];
        base_[i] = c ? atomicAdd(&bincursor[i], c) : 0;
        h[i] = 0;
    }
    __syncthreads();
    for (int e = blockIdx.x * 512 + threadIdx.x; e < ne; e += stride) {
        int dd = ei[(size_t)ne + e];
        int ss = ei[e];
        float w = ew[e];
        int bin = dd >> 5;
        int r = atomicAdd(&h[bin], 1);
        ptmp[base_[bin] + r] =
            make_uint2((unsigned)ss | ((unsigned)(dd & 31) << 17),
                       __float_as_uint(w));
    }
}

// P4: within-bin counting sort -> fully dst-sorted (src,w) + rp[] CSR.
// LDS-staged (single global read) with global-path fallback for huge bins.
__global__ __launch_bounds__(256) void binsort_kernel(
    const uint2* __restrict__ ptmp, const int* __restrict__ binstart,
    uint2* __restrict__ epair, int* __restrict__ rp) {
    int b = blockIdx.x;
    int tid = threadIdx.x;
    int beg = binstart[b], end = binstart[b + 1];
    int nE = end - beg;
    __shared__ uint2 sbuf[SORTCAP];
    __shared__ int cnt[BINB];
    __shared__ int cur[BINB];
    if (tid < BINB) cnt[tid] = 0;
    __syncthreads();
    if (nE <= SORTCAP) {
        for (int i = tid; i < nE; i += 256) {
            uint2 p = ptmp[beg + i];
            sbuf[i] = p;
            atomicAdd(&cnt[(p.x >> 17) & 31], 1);
        }
        __syncthreads();
        if (tid < BINB) {
            int v = cnt[tid];
            int x = v;
            #pragma unroll
            for (int d = 1; d < BINB; d <<= 1) {
                int y = __shfl_up(x, (unsigned)d, BINB);
                if (tid >= d) x += y;
            }
            int start = beg + x - v;
            cur[tid] = start;
            rp[b * BINB + tid] = start;
        }
        __syncthreads();
        for (int i = tid; i < nE; i += 256) {
            uint2 p = sbuf[i];
            int dl = (p.x >> 17) & 31;
            int pos = atomicAdd(&cur[dl], 1);
            epair[pos] = make_uint2(p.x & 0x1FFFF, p.y);
        }
    } else {  // fallback: two-pass over global (statistically never taken)
        for (int i = beg + tid; i < end; i += 256)
            atomicAdd(&cnt[(ptmp[i].x >> 17) & 31], 1);
        __syncthreads();
        if (tid < BINB) {
            int v = cnt[tid];
            int x = v;
            #pragma unroll
            for (int d = 1; d < BINB; d <<= 1) {
                int y = __shfl_up(x, (unsigned)d, BINB);
                if (tid >= d) x += y;
            }
            int start = beg + x - v;
            cur[tid] = start;
            rp[b * BINB + tid] = start;
        }
        __syncthreads();
        for (int i = beg + tid; i < end; i += 256) {
            uint2 p = ptmp[i];
            int dl = (p.x >> 17) & 31;
            int pos = atomicAdd(&cur[dl], 1);
            epair[pos] = make_uint2(p.x & 0x1FFFF, p.y);
        }
    }
}

// ---------------- fp32 -> bf16 node table (pad rows zeroed) ----------------
__global__ void cvt_node_kernel(const float* __restrict__ in, ushort_t* __restrict__ out,
                                long n_valid, long n_total) {
    long g = (long)blockIdx.x * blockDim.x + threadIdx.x;
    long ng = n_total >> 2;
    for (long i = g; i < ng; i += (long)gridDim.x * blockDim.x) {
        long e = i << 2;
        uint2 o;
        if (e < n_valid) {
            float4 v = ((const float4*)in)[i];
            o.x = pack2(v.x, v.y);
            o.y = pack2(v.z, v.w);
        } else {
            o.x = 0u; o.y = 0u;
        }
        ((uint2*)out)[i] = o;
    }
}

// ---- weight transposes, 4 matrices in one launch (z selects) ----
__global__ __launch_bounds__(256) void transpose_w4_kernel(
    const float* __restrict__ Wa, const float* __restrict__ Wb,
    const float* __restrict__ Wc, const float* __restrict__ Wd,
    ushort_t* __restrict__ Ta, ushort_t* __restrict__ Tb,
    ushort_t* __restrict__ Tc, ushort_t* __restrict__ Td) {
    const float* W;
    ushort_t* Wt;
    switch (blockIdx.z) {
        case 0: W = Wa; Wt = Ta; break;
        case 1: W = Wb; Wt = Tb; break;
        case 2: W = Wc; Wt = Tc; break;
        default: W = Wd; Wt = Td; break;
    }
    __shared__ float t[32][33];
    int bx = blockIdx.x * 32;   // n base
    int by = blockIdx.y * 32;   // k base
    int lx = threadIdx.x & 31, ly = threadIdx.x >> 5;   // 32 x 8
    #pragma unroll
    for (int i = 0; i < 32; i += 8)
        t[ly + i][lx] = W[(size_t)(by + ly + i) * 256 + bx + lx];
    __syncthreads();
    #pragma unroll
    for (int i = 0; i < 32; i += 8)
        Wt[(size_t)(bx + ly + i) * 256 + by + lx] = f2bfu(t[lx][ly + i]);
}

// ---------------- weighted aggregation over bf16 rows ----------------
// One wave per dst row, two 32-lane halves gather different edges with
// 16B/lane uint4 loads; 16-edge unrolled main loop = 8 gathers in flight.
__device__ __forceinline__ void acc8(float* a, uint4 v, float w) {
    a[0] += w * blo(v.x); a[1] += w * bhi(v.x);
    a[2] += w * blo(v.y); a[3] += w * bhi(v.y);
    a[4] += w * blo(v.z); a[5] += w * bhi(v.z);
    a[6] += w * blo(v.w); a[7] += w * bhi(v.w);
}

__global__ __launch_bounds__(256) void agg_bf16_kernel(
    const ushort_t* __restrict__ x, const int* __restrict__ rp,
    const uint2* __restrict__ ep, ushort_t* __restrict__ out, int n) {
    int wv = (int)(((size_t)blockIdx.x * blockDim.x + threadIdx.x) >> 6);
    int lane = threadIdx.x & 63;
    if (wv >= n) return;
    int half = lane >> 5;
    int l32 = lane & 31;
    int beg = rp[wv], end = rp[wv + 1];
    float a[8] = {};
    int e = beg;
    for (; e + 16 <= end; e += 16) {
        uint2 p0 = ep[e + half];
        uint2 p1 = ep[e + 2 + half];
        uint2 p2 = ep[e + 4 + half];
        uint2 p3 = ep[e + 6 + half];
        uint2 p4 = ep[e + 8 + half];
        uint2 p5 = ep[e + 10 + half];
        uint2 p6 = ep[e + 12 + half];
        uint2 p7 = ep[e + 14 + half];
        uint4 v0 = ((const uint4*)(x + (size_t)p0.x * D))[l32];
        uint4 v1 = ((const uint4*)(x + (size_t)p1.x * D))[l32];
        uint4 v2 = ((const uint4*)(x + (size_t)p2.x * D))[l32];
        uint4 v3 = ((const uint4*)(x + (size_t)p3.x * D))[l32];
        uint4 v4 = ((const uint4*)(x + (size_t)p4.x * D))[l32];
        uint4 v5 = ((const uint4*)(x + (size_t)p5.x * D))[l32];
        uint4 v6 = ((const uint4*)(x + (size_t)p6.x * D))[l32];
        uint4 v7 = ((const uint4*)(x + (size_t)p7.x * D))[l32];
        acc8(a, v0, __uint_as_float(p0.y));
        acc8(a, v1, __uint_as_float(p1.y));
        acc8(a, v2, __uint_as_float(p2.y));
        acc8(a, v3, __uint_as_float(p3.y));
        acc8(a, v4, __uint_as_float(p4.y));
        acc8(a, v5, __uint_as_float(p5.y));
        acc8(a, v6, __uint_as_float(p6.y));
        acc8(a, v7, __uint_as_float(p7.y));
    }
    for (; e + 4 <= end; e += 4) {
        uint2 p0 = ep[e + half];
        uint2 p1 = ep[e + 2 + half];
        uint4 v0 = ((const uint4*)(x + (size_t)p0.x * D))[l32];
        uint4 v1 = ((const uint4*)(x + (size_t)p1.x * D))[l32];
        acc8(a, v0, __uint_as_float(p0.y));
        acc8(a, v1, __uint_as_float(p1.y));
    }
    for (; e + 2 <= end; e += 2) {
        uint2 p0 = ep[e + half];
        uint4 v0 = ((const uint4*)(x + (size_t)p0.x * D))[l32];
        acc8(a, v0, __uint_as_float(p0.y));
    }
    if (e < end) {   // odd tail: both halves read the same row, upper weight 0
        uint2 p0 = ep[e];
        uint4 v0 = ((const uint4*)(x + (size_t)p0.x * D))[l32];
        acc8(a, v0, half ? 0.f : __uint_as_float(p0.y));
    }
    #pragma unroll
    for (int j = 0; j < 8; ++j) a[j] += __shfl_xor(a[j], 32, 64);
    if (half == 0) {
        uint4 o;
        o.x = pack2(a[0], a[1]); o.y = pack2(a[2], a[3]);
        o.z = pack2(a[4], a[5]); o.w = pack2(a[6], a[7]);
        ((uint4*)(out + (size_t)wv * D))[l32] = o;
    }
}

// ---------------- bf16 MFMA GEMM: 128x256 tile, BK=32, 8 waves (512 thr) ----
// A bf16 row-major [*,256]; Wt = W^T bf16. LDS XOR-swizzle c^=((row>>1)&3).
// MODE 0: relu(A@W+bias) -> bf16 out
// MODE 1: A@W+bias       -> bf16 out
// MODE 2: tout[row] = sum_col tanh((A@W)[row,col]) * u[col]  (no out store)
template<int MODE>
__global__ __launch_bounds__(512) void mfma_gemm_kernel(
    const ushort_t* __restrict__ A, const ushort_t* __restrict__ Wt,
    const float* __restrict__ bias, ushort_t* __restrict__ out,
    const float* __restrict__ u, float* __restrict__ tout, int mvalid) {
    __shared__ __align__(16) ushort_t As[128 * 32];
    __shared__ __align__(16) ushort_t Bs[256 * 32];
    __shared__ float s_t[128];
    const int tid = threadIdx.x;
    const int lane = tid & 63;
    const int wv = tid >> 6;           // 0..7
    const int wr = wv >> 2, wc = wv & 3;
    const size_t brow = (size_t)blockIdx.x * 128;

    const int ra = tid >> 2, ca = tid & 3;
    const int rb1 = ra + 128;
    const int csa = ca ^ ((ra >> 1) & 3);
    const ushort_t* gA  = A  + (brow + ra) * 256 + ca * 8;
    const ushort_t* gB0 = Wt + (size_t)ra  * 256 + ca * 8;
    const ushort_t* gB1 = Wt + (size_t)rb1 * 256 + ca * 8;
    ushort_t* lA  = As + ra * 32 + csa * 8;
    ushort_t* lB0 = Bs + ra * 32 + csa * 8;
    ushort_t* lB1 = Bs + rb1 * 32 + csa * 8;

    const int g = lane >> 4, rl = lane & 15;
    int aoff[4], boff[4];
    #pragma unroll
    for (int m = 0; m < 4; ++m) {
        int row = wr * 64 + m * 16 + rl;
        aoff[m] = row * 32 + (g ^ ((row >> 1) & 3)) * 8;
    }
    #pragma unroll
    for (int n = 0; n < 4; ++n) {
        int row = wc * 64 + n * 16 + rl;
        boff[n] = row * 32 + (g ^ ((row >> 1) & 3)) * 8;
    }

    if (MODE == 2 && tid < 128) s_t[tid] = 0.f;

    f32x4 acc[4][4] = {};
    uint4 va  = *(const uint4*)gA;
    uint4 vb0 = *(const uint4*)gB0;
    uint4 vb1 = *(const uint4*)gB1;

    for (int ks = 0; ks < 8; ++ks) {
        *(uint4*)lA = va; *(uint4*)lB0 = vb0; *(uint4*)lB1 = vb1;
        __syncthreads();
        if (ks < 7) {
            int k0 = (ks + 1) * 32;
            va  = *(const uint4*)(gA + k0);
            vb0 = *(const uint4*)(gB0 + k0);
            vb1 = *(const uint4*)(gB1 + k0);
        }
        short8 af[4], bfv[4];
        #pragma unroll
        for (int m = 0; m < 4; ++m) af[m] = *(const short8*)(As + aoff[m]);
        #pragma unroll
        for (int n = 0; n < 4; ++n) bfv[n] = *(const short8*)(Bs + boff[n]);
        #pragma unroll
        for (int m = 0; m < 4; ++m)
            #pragma unroll
            for (int n = 0; n < 4; ++n)
                acc[m][n] = __builtin_amdgcn_mfma_f32_16x16x32_bf16(
                    af[m], bfv[n], acc[m][n], 0, 0, 0);
        __syncthreads();
    }

    if (MODE == 2) {
        float uvv[4];
        #pragma unroll
        for (int n = 0; n < 4; ++n) uvv[n] = u[wc * 64 + n * 16 + rl];
        #pragma unroll
        for (int m = 0; m < 4; ++m) {
            #pragma unroll
            for (int r = 0; r < 4; ++r) {
                float v = 0.f;
                #pragma unroll
                for (int n = 0; n < 4; ++n) v += tanhf(acc[m][n][r]) * uvv[n];
                v += __shfl_xor(v, 1, 64);
                v += __shfl_xor(v, 2, 64);
                v += __shfl_xor(v, 4, 64);
                v += __shfl_xor(v, 8, 64);
                if (rl == 0) atomicAdd(&s_t[wr * 64 + m * 16 + g * 4 + r], v);
            }
        }
        __syncthreads();
        if (tid < 128 && brow + tid < (size_t)mvalid) tout[brow + tid] = s_t[tid];
    } else {
        #pragma unroll
        for (int m = 0; m < 4; ++m) {
            #pragma unroll
            for (int r = 0; r < 4; ++r) {
                size_t row = brow + wr * 64 + m * 16 + g * 4 + r;
                #pragma unroll
                for (int n = 0; n < 4; ++n) {
                    int col = wc * 64 + n * 16 + rl;
                    float v = acc[m][n][r] + bias[col];
                    if (MODE == 0) v = fmaxf(v, 0.f);
                    out[row * 256 + col] = f2bfu(v);
                }
            }
        }
    }
}

// ---------------- code attention: one block per (b,v), emb bf16 -> vemb bf16
__global__ __launch_bounds__(256) void code_attn_kernel(
    const int* __restrict__ codes, const float* __restrict__ t,
    const ushort_t* __restrict__ emb, ushort_t* __restrict__ vembB,
    int* __restrict__ vmask) {
    int bv = blockIdx.x;
    int tid = threadIdx.x;
    __shared__ int s_codes[CODES];
    __shared__ float s_av[CODES];
    __shared__ int s_valid;
    if (tid < 64) {
        int c = codes[(size_t)bv * CODES + tid];
        s_codes[tid] = c;
        float e = (c > 0) ? t[c] : NEG_INF;
        float m = e;
        #pragma unroll
        for (int d = 32; d; d >>= 1) m = fmaxf(m, __shfl_xor(m, d, 64));
        float ex = expf(e - m);
        float s = ex;
        #pragma unroll
        for (int d = 32; d; d >>= 1) s += __shfl_xor(s, d, 64);
        s_av[tid] = ex / s;
        if (tid == 0) s_valid = (m > -1e8f) ? 1 : 0;
    }
    __syncthreads();
    float acc = 0.f;
    #pragma unroll 4
    for (int c = 0; c < CODES; ++c) {
        int node = s_codes[c];
        if (node > 0) acc += s_av[c] * bf2f(emb[(size_t)node * D + tid]);
    }
    int valid = s_valid;
    vembB[(size_t)bv * D + tid] = f2bfu(valid ? acc : 0.f);
    if (tid == 0) vmask[bv] = valid;
}

// per-patient: masked softmax over visit scores, pemb = sum ap * vemb
__global__ __launch_bounds__(256) void patient_kernel(
    const ushort_t* __restrict__ vembB, const float* __restrict__ epr,
    const int* __restrict__ vmask, float* __restrict__ pemb) {
    int b = blockIdx.x;
    int tid = threadIdx.x;
    __shared__ float s_ap[VIS];
    __shared__ int s_any;
    if (tid < 64) {
        float e = -3e38f;
        if (tid < VIS) e = vmask[b * VIS + tid] ? epr[b * VIS + tid] : NEG_INF;
        float m = e;
        #pragma unroll
        for (int d = 32; d; d >>= 1) m = fmaxf(m, __shfl_xor(m, d, 64));
        float ex = (tid < VIS) ? expf(e - m) : 0.f;
        float s = ex;
        #pragma unroll
        for (int d = 32; d; d >>= 1) s += __shfl_xor(s, d, 64);
        if (tid < VIS) s_ap[tid] = ex / s;
        if (tid == 0) s_any = (m > -1e8f) ? 1 : 0;
    }
    __syncthreads();
    float acc = 0.f;
    for (int v = 0; v < VIS; ++v)
        acc += s_ap[v] * bf2f(vembB[((size_t)b * VIS + v) * D + tid]);
    pemb[b * D + tid] = s_any ? acc : 0.f;
}

__global__ __launch_bounds__(256) void gemm_rowcol(
    const float* __restrict__ A, const float* __restrict__ W,
    const float* __restrict__ bias, float* __restrict__ C,
    int M, int N, int K, int act) {
    int row = blockIdx.x;
    int col = blockIdx.y * 256 + threadIdx.x;
    if (col >= N) return;
    const float* a = A + (size_t)row * K;
    float acc = bias ? bias[col] : 0.f;
    #pragma unroll 4
    for (int k = 0; k < K; ++k) acc = fmaf(a[k], W[(size_t)k * N + col], acc);
    if (act == 1) acc = fmaxf(acc, 0.f);
    C[(size_t)row * N + col] = acc;
}

extern "C" void kernel_launch(void* const* d_in, const int* in_sizes, int n_in,
                              void* d_out, int out_size, void* d_ws, size_t ws_size,
                              hipStream_t stream) {
    const int* edge_index    = (const int*)d_in[0];
    const float* edge_weight = (const float*)d_in[1];
    const int* codes         = (const int*)d_in[2];
    const float* node_emb    = (const float*)d_in[3];
    const float* W1 = (const float*)d_in[4];
    const float* b1 = (const float*)d_in[5];
    const float* W2 = (const float*)d_in[6];
    const float* b2 = (const float*)d_in[7];
    const float* Wv = (const float*)d_in[8];
    const float* uv = (const float*)d_in[9];
    const float* Wp = (const float*)d_in[10];
    const float* up = (const float*)d_in[11];
    const float* Wd1 = (const float*)d_in[12];
    const float* bd1 = (const float*)d_in[13];
    const float* Wd2 = (const float*)d_in[14];
    const float* bd2 = (const float*)d_in[15];
    const float* Wd3 = (const float*)d_in[16];
    const float* bd3 = (const float*)d_in[17];

    const int NE = in_sizes[1];          // 3,200,000
    const int NN = in_sizes[3] / D;      // 100,000

    char* ws = (char*)d_ws;
    size_t off = 0;
    auto alloc = [&](size_t bytes) -> void* {
        void* p = ws + off;
        off += (bytes + 255) & ~(size_t)255;
        return p;
    };
    ushort_t* nbf  = (ushort_t*)alloc((size_t)MPAD * D * 2);  // node table / h
    ushort_t* aggb = (ushort_t*)alloc((size_t)MPAD * D * 2);  // agg out
    ushort_t* embB = (ushort_t*)alloc((size_t)MPAD * D * 2);  // emb (bf16)
    uint2* ptmp   = (uint2*)alloc((size_t)NE * 8);            // bin-partitioned
    uint2* epair  = (uint2*)alloc((size_t)NE * 8);            // dst-sorted (src,w)
    int* bincount = (int*)alloc((size_t)NBIN * 4);
    int* binstart = (int*)alloc((size_t)(NBIN + 1) * 4);
    int* bincursor= (int*)alloc((size_t)NBIN * 4);
    int* rp       = (int*)alloc((size_t)(NN + 1) * 4);
    ushort_t* W1t = (ushort_t*)alloc(256 * 256 * 2);
    ushort_t* W2t = (ushort_t*)alloc(256 * 256 * 2);
    ushort_t* Wvt = (ushort_t*)alloc(256 * 256 * 2);
    ushort_t* Wpt = (ushort_t*)alloc(256 * 256 * 2);
    float* tbuf  = (float*)alloc((size_t)NN * 4);
    ushort_t* vembB = (ushort_t*)alloc((size_t)BPAT * VIS * D * 2);
    int*   vmask = (int*)  alloc((size_t)BPAT * VIS * 4);
    float* epr   = (float*)alloc((size_t)BPAT * VIS * 4);
    float* pemb  = (float*)alloc((size_t)BPAT * D * 4);
    float* h1    = (float*)alloc((size_t)BPAT * 512 * 4);
    float* h2    = (float*)alloc((size_t)BPAT * D * 4);
    (void)ws_size; (void)n_in; (void)out_size;

    const int ab = NN / 4;                    // one wave/row, 4 waves/block

    // --- binned partition + within-bin sort -> dst-sorted CSR ---
    hipMemsetAsync(bincount, 0, (size_t)NBIN * 4, stream);
    bin_count_kernel<<<256, 512, 0, stream>>>(edge_index, bincount, NE);
    bin_scan_kernel<<<1, 64, 0, stream>>>(bincount, binstart, bincursor, rp, NE, NN);
    partition_kernel<<<128, 512, 0, stream>>>(edge_index, edge_weight,
                                              bincursor, ptmp, NE);
    binsort_kernel<<<NBIN, 256, 0, stream>>>(ptmp, binstart, epair, rp);

    // --- bf16 conversions ---
    cvt_node_kernel<<<2048, 256, 0, stream>>>(node_emb, nbf, (long)NN * D, (long)MPAD * D);
    transpose_w4_kernel<<<dim3(8, 8, 4), 256, 0, stream>>>(
        W1, W2, Wv, Wp, W1t, W2t, Wvt, Wpt);

    // --- GCN layer 1: h = relu(agg(x) @ W1 + b1) ---
    agg_bf16_kernel<<<ab, 256, 0, stream>>>(nbf, rp, epair, aggb, NN);
    mfma_gemm_kernel<0><<<MPAD / 128, 512, 0, stream>>>(
        aggb, W1t, b1, nbf, nullptr, nullptr, 0);

    // --- GCN layer 2: emb = agg(h) @ W2 + b2 ---
    agg_bf16_kernel<<<ab, 256, 0, stream>>>(nbf, rp, epair, aggb, NN);
    mfma_gemm_kernel<1><<<MPAD / 128, 512, 0, stream>>>(
        aggb, W2t, b2, embB, nullptr, nullptr, 0);

    // --- fused per-node code score: t = tanh(emb @ Wv) @ uv ---
    mfma_gemm_kernel<2><<<MPAD / 128, 512, 0, stream>>>(
        embB, Wvt, nullptr, nullptr, uv, tbuf, NN);

    // --- code attention -> vemb (bf16) ---
    code_attn_kernel<<<BPAT * VIS, 256, 0, stream>>>(codes, tbuf, embB, vembB, vmask);

    // --- fused visit score: ep = tanh(vemb @ Wp) @ up  (3200 = 25*128 rows) ---
    mfma_gemm_kernel<2><<<BPAT * VIS / 128, 512, 0, stream>>>(
        vembB, Wpt, nullptr, nullptr, up, epr, BPAT * VIS);

    // --- patient attention + decoder ---
    patient_kernel<<<BPAT, 256, 0, stream>>>(vembB, epr, vmask, pemb);
    gemm_rowcol<<<dim3(BPAT, 2), 256, 0, stream>>>(pemb, Wd1, bd1, h1, BPAT, 512, D, 1);
    gemm_rowcol<<<dim3(BPAT, 1), 256, 0, stream>>>(h1, Wd2, bd2, h2, BPAT, D, 512, 1);
    gemm_rowcol<<<dim3(BPAT, 4), 256, 0, stream>>>(h2, Wd3, bd3, (float*)d_out, BPAT, 1000, D, 0);
}